// Round 7
// baseline (217.463 us; speedup 1.0000x reference)
//
#include <hip/hip_runtime.h>
#include <hip/hip_bf16.h>

// ---------------- types & helpers ----------------
typedef short bf16x8 __attribute__((ext_vector_type(8)));
typedef float f32x4  __attribute__((ext_vector_type(4)));
typedef unsigned short u16x4 __attribute__((ext_vector_type(4)));

#define CDIM   768
#define NQKV   2304
#define MROWS  8192
#define TSEQ   2048
#define HD     64
#define NHEAD  12
#define BHTOT  48

__device__ __forceinline__ unsigned short f2bf(float f) {
    unsigned int x;
    __builtin_memcpy(&x, &f, 4);
    unsigned int r = (x + 0x7fffu + ((x >> 16) & 1u)) >> 16;
    return (unsigned short)r;
}

__device__ __forceinline__ unsigned int pkbf(float a, float b) {
    unsigned int ua, ub;
    __builtin_memcpy(&ua, &a, 4);
    __builtin_memcpy(&ub, &b, 4);
    return __builtin_amdgcn_perm(ua + 0x8000u, ub + 0x8000u, 0x03020706u);
}

__device__ __forceinline__ f32x4 mfma16(bf16x8 a, bf16x8 b, f32x4 c) {
    return __builtin_amdgcn_mfma_f32_16x16x32_bf16(a, b, c, 0, 0, 0);
}

__device__ __forceinline__ void gl_lds16(const unsigned short* g, unsigned short* l) {
    __builtin_amdgcn_global_load_lds(
        (__attribute__((address_space(1))) void*)(g),
        (__attribute__((address_space(3))) void*)(l),
        16, 0, 0);
}

// ---------------- kernel 0: prep = W transpose+cvt + X cvt ----------------
__global__ __launch_bounds__(256) void prep(
    const float* __restrict__ X, const float* __restrict__ W,
    unsigned short* __restrict__ Xb, unsigned short* __restrict__ Wt)
{
    const int tid = threadIdx.x, blk = blockIdx.x;
    if (blk < 432) {
        __shared__ __align__(16) unsigned short tile[64][72];
        const int bx = blk % 36, by = blk / 36;
#pragma unroll
        for (int c = 0; c < 4; c++) {
            int chunk = tid + 256 * c;
            int r = chunk >> 4, cc = chunk & 15;
            f32x4 v = *(const f32x4*)(W + (size_t)(by * 64 + r) * NQKV + bx * 64 + cc * 4);
#pragma unroll
            for (int j = 0; j < 4; j++) tile[cc * 4 + j][r] = f2bf(v[j]);
        }
        __syncthreads();
#pragma unroll
        for (int c = 0; c < 2; c++) {
            int chunk = tid + 256 * c;
            int r = chunk >> 3, cc = chunk & 7;
            bf16x8 v;
#pragma unroll
            for (int j = 0; j < 8; j++) v[j] = (short)tile[r][cc * 8 + j];
            *(bf16x8*)(Wt + (size_t)(bx * 64 + r) * CDIM + by * 64 + cc * 8) = v;
        }
    }
    for (size_t i4 = (size_t)blk * 256 + tid; i4 < (size_t)(MROWS * CDIM / 4);
         i4 += (size_t)448 * 256) {
        f32x4 v = *(const f32x4*)(X + i4 * 4);
        u16x4 o;
#pragma unroll
        for (int j = 0; j < 4; j++) o[j] = f2bf(v[j]);
        *(u16x4*)(Xb + i4 * 4) = o;
    }
}

// ---------------- kernel 1: QKV GEMM (BM=256, BN=128, BK=64, 512 thr) ----------------
// R0 baseline (proven 57.5us profiled). 8 waves, each 64x64. XOR-swizzled LDS,
// conflict-free b128 reads. Q pre-scaled by 0.125. XCD-colocated m-tiles.
#define BK 64

__global__ __launch_bounds__(512, 4) void qkv_gemm(
    const unsigned short* __restrict__ X,    // (8192, 768) bf16
    const unsigned short* __restrict__ Wt,   // (2304, 768) bf16
    const float* __restrict__ Bias,          // (2304) fp32
    unsigned short* __restrict__ Q,
    unsigned short* __restrict__ Km,
    unsigned short* __restrict__ Vt)
{
    __shared__ __align__(16) unsigned short As[256 * BK];  // 32 KB
    __shared__ __align__(16) unsigned short Bs[128 * BK];  // 16 KB
    const int tid  = threadIdx.x;
    const int wave = tid >> 6, lane = tid & 63;
    const int quad = lane >> 4, m16 = lane & 15;
    const int wr = wave >> 1, wc = wave & 1;

    const int t   = blockIdx.x;                // 0..575
    const int xcd = t & 7, s = t >> 3;         // s: 0..71
    const int m0  = (xcd * 4 + (s & 3)) * 256;
    const int n0  = (s >> 2) * 128;

    f32x4 acc[4][4];
#pragma unroll
    for (int i = 0; i < 4; i++)
#pragma unroll
        for (int j = 0; j < 4; j++) acc[i][j] = f32x4{0.f, 0.f, 0.f, 0.f};

    const unsigned short* xb = X + (size_t)m0 * CDIM;
    const unsigned short* wb = Wt + (size_t)n0 * CDIM;

    const int spos = lane & 7;
    const int rb = m16 & 7;
    int arow[4], brow[2];
#pragma unroll
    for (int c = 0; c < 4; c++) arow[c] = (wave * 256 + c * 64 + lane) >> 3;
#pragma unroll
    for (int c = 0; c < 2; c++) brow[c] = (wave * 128 + c * 64 + lane) >> 3;

    for (int k0 = 0; k0 < CDIM; k0 += BK) {
#pragma unroll
        for (int c = 0; c < 4; c++) {
            int row = arow[c], ch = spos ^ (row & 7);
            gl_lds16(xb + (size_t)row * CDIM + k0 + ch * 8, As + wave * 2048 + c * 512);
        }
#pragma unroll
        for (int c = 0; c < 2; c++) {
            int row = brow[c], ch = spos ^ (row & 7);
            gl_lds16(wb + (size_t)row * CDIM + k0 + ch * 8, Bs + wave * 1024 + c * 512);
        }
        __syncthreads();
#pragma unroll
        for (int ks = 0; ks < 2; ks++) {
            bf16x8 af[4], bfg[4];
#pragma unroll
            for (int u = 0; u < 4; u++) {
                int rowa = wr * 64 + u * 16 + m16;
                int rowb = wc * 64 + u * 16 + m16;
                int pos = (ks * 4 + quad) ^ rb;
                af[u]  = *(const bf16x8*)(As + rowa * 64 + pos * 8);
                bfg[u] = *(const bf16x8*)(Bs + rowb * 64 + pos * 8);
            }
#pragma unroll
            for (int i = 0; i < 4; i++)
#pragma unroll
                for (int j = 0; j < 4; j++)
                    acc[i][j] = mfma16(af[i], bfg[j], acc[i][j]);
        }
        __syncthreads();
    }

    const int region = n0 / CDIM;
    const float qscale = (region == 0) ? 0.125f : 1.0f;
#pragma unroll
    for (int i = 0; i < 4; i++) {
        int row = m0 + wr * 64 + i * 16 + quad * 4;
#pragma unroll
        for (int j = 0; j < 4; j++) {
            int gcol = n0 + wc * 64 + j * 16 + m16;
            int cc = gcol - region * CDIM;
            int h = cc >> 6, d = cc & 63;
            float bv = Bias[gcol];
#pragma unroll
            for (int r = 0; r < 4; r++) {
                int gm = row + r;
                int b = gm >> 11, tq = gm & 2047;
                int bh = b * NHEAD + h;
                unsigned short o = f2bf((acc[i][j][r] + bv) * qscale);
                if (region == 0)      Q[((size_t)bh * TSEQ + tq) * HD + d] = o;
                else if (region == 1) Km[((size_t)bh * TSEQ + tq) * HD + d] = o;
                else                  Vt[((size_t)bh * HD + d) * TSEQ + tq] = o;
            }
        }
    }
}

// ---------------- kernel 2: causal relu-attention (S^T formulation) ----------------
// R7: QBLK 128 -> 256 rows, 8 waves (512 thr) share one staged 128-wide K/V
// tile. Same 32KB LDS, same swizzles (conflicts==0), same R5 split-wait
// (vmcnt(2)=K-only -> QK while V flies -> vmcnt(0) -> PV). Amortization:
// staged bytes and barriers per MFMA halve (R6 showed attn is sync-bound:
// MfmaUtil 13%, VALU 19%, HBM 3%). V back in LDS (R6's direct-global V
// serialized PV on L2 latency: 50 -> 78.6us). Causal: block q-rows
// [it*256,+256), jt <= 2it+1; waves above diagonal skip compute (barriers
// outside guard); mask compares GLOBAL i,j. Longest blocks first.
#define LDSK 0
#define LDSV 8192

__global__ __launch_bounds__(512, 4) void attn(
    const unsigned short* __restrict__ Q,
    const unsigned short* __restrict__ Kmat,
    const unsigned short* __restrict__ Vt,
    float* __restrict__ Out)
{
    __shared__ __align__(16) unsigned short S[16384];  // K 16KB | V 16KB

    const int tid  = threadIdx.x;
    const int wave = tid >> 6, lane = tid & 63;   // 8 waves
    const int q4 = lane >> 4, m16 = lane & 15;
    const int q8 = m16 >> 2, m3 = m16 & 3;

    const int xcd = blockIdx.x & 7;
    const int idx = blockIdx.x >> 3;        // 0..47
    const int bh  = xcd * 6 + (idx % 6);
    const int itv = 7 - (idx / 6);          // 7..0, longest first
    const int i0  = itv * 256;
    const int i0w = i0 + wave * 32;         // this wave's q-row base
    const int jtmax = 2 * itv + 1;

    const unsigned short* qb = Q    + (size_t)bh * TSEQ * HD;
    const unsigned short* kb = Kmat + (size_t)bh * TSEQ * HD;
    const unsigned short* vb = Vt   + (size_t)bh * HD * TSEQ;

    bf16x8 qf[2][2];
#pragma unroll
    for (int si = 0; si < 2; si++)
#pragma unroll
        for (int ks = 0; ks < 2; ks++)
            qf[si][ks] = *(const bf16x8*)(qb +
                (size_t)(i0w + si * 16 + m16) * HD + ks * 32 + q4 * 8);

    f32x4 oacc[2][4];
#pragma unroll
    for (int si = 0; si < 2; si++)
#pragma unroll
        for (int dn = 0; dn < 4; dn++) oacc[si][dn] = f32x4{0.f, 0.f, 0.f, 0.f};

    const int fr  = ((q8 & 1) << 2) | m3;
    const int kx0 = (q4 ^ fr) * 8;
    const int kx1 = kx0 ^ 32;
    const int krb = (q8 * 8 + m3) * 64;

    // per-wave staging offsets: 2 K chunks + 2 V chunks (1KB each), 8 waves
    int ksrow[2], kschk[2], vsrow[2], vschk[2];
#pragma unroll
    for (int cc = 0; cc < 2; cc++) {
        int cs = wave * 2 + cc;                    // 0..15
        ksrow[cc] = cs * 8 + (lane >> 3);
        kschk[cc] = (lane & 7) ^ ((((ksrow[cc] >> 3) & 1) << 2) | (ksrow[cc] & 3));
        vsrow[cc] = cs * 4 + (lane >> 4);
        vschk[cc] = (m16 & 8) | ((m16 ^ vsrow[cc]) & 7);
    }

    for (int jt = 0; jt <= jtmax; jt++) {
        const int j0 = jt * 128;
        // ---- stage K (2 chunks) then V (2 chunks) per wave ----
#pragma unroll
        for (int cc = 0; cc < 2; cc++)
            gl_lds16(kb + (size_t)(j0 + ksrow[cc]) * HD + kschk[cc] * 8,
                     &S[LDSK] + (wave * 2 + cc) * 512);
#pragma unroll
        for (int cc = 0; cc < 2; cc++)
            gl_lds16(vb + (size_t)vsrow[cc] * TSEQ + j0 + vschk[cc] * 8,
                     &S[LDSV] + (wave * 2 + cc) * 512);
        // wait own K chunks only (V still in flight), sync
        asm volatile("s_waitcnt vmcnt(2)" ::: "memory");
        __builtin_amdgcn_s_barrier();
        __builtin_amdgcn_sched_barrier(0);

        const bool live = (j0 <= i0w + 31);         // any unmasked element?
        const bool diag = live && (j0 + 127 > i0w); // needs elementwise mask?

        unsigned int pk[4][2][2][2];
        if (live) {
#pragma unroll
            for (int kk = 0; kk < 4; kk++) {
                const int kb0 = kk * 2048 + krb;
                bf16x8 kf_e0 = *(const bf16x8*)(&S[LDSK] + kb0 + kx0);
                bf16x8 kf_e1 = *(const bf16x8*)(&S[LDSK] + kb0 + kx1);
                bf16x8 kf_o0 = *(const bf16x8*)(&S[LDSK] + kb0 + 256 + kx0);
                bf16x8 kf_o1 = *(const bf16x8*)(&S[LDSK] + kb0 + 256 + kx1);

                f32x4 sacc[2][2];
#pragma unroll
                for (int o = 0; o < 2; o++)
#pragma unroll
                    for (int si = 0; si < 2; si++) sacc[o][si] = f32x4{0.f, 0.f, 0.f, 0.f};
#pragma unroll
                for (int si = 0; si < 2; si++) {
                    sacc[0][si] = mfma16(kf_e0, qf[si][0], sacc[0][si]);
                    sacc[0][si] = mfma16(kf_e1, qf[si][1], sacc[0][si]);
                    sacc[1][si] = mfma16(kf_o0, qf[si][0], sacc[1][si]);
                    sacc[1][si] = mfma16(kf_o1, qf[si][1], sacc[1][si]);
                }

#pragma unroll
                for (int o = 0; o < 2; o++)
#pragma unroll
                    for (int si = 0; si < 2; si++) {
                        f32x4 v = sacc[o][si];
                        if (diag) {
#pragma unroll
                            for (int r = 0; r < 4; r++) {
                                int gj = j0 + kk * 32 + q4 * 8 + o * 4 + r;
                                int gi = i0w + si * 16 + m16;
                                if (gj > gi) v[r] = 0.f;
                            }
                        }
#pragma unroll
                        for (int r = 0; r < 4; r++) v[r] = fmaxf(v[r], 0.f);
                        pk[kk][o][si][0] = pkbf(v[0], v[1]);
                        pk[kk][o][si][1] = pkbf(v[2], v[3]);
                    }
            }
        }

        // ---- V now resident: drain + sync, then PV ----
        asm volatile("s_waitcnt vmcnt(0)" ::: "memory");
        __builtin_amdgcn_s_barrier();
        __builtin_amdgcn_sched_barrier(0);

        if (live) {
#pragma unroll
            for (int kk = 0; kk < 4; kk++) {
#pragma unroll
                for (int dn = 0; dn < 4; dn++) {
                    int vsw = ((kk * 4 + q4) ^ (m16 & 7)) * 8;
                    bf16x8 vf = *(const bf16x8*)(&S[LDSV] + (dn * 16 + m16) * 128 + vsw);
#pragma unroll
                    for (int si = 0; si < 2; si++) {
                        union { bf16x8 v; unsigned int u[4]; } af;
                        af.u[0] = pk[kk][0][si][0];
                        af.u[1] = pk[kk][0][si][1];
                        af.u[2] = pk[kk][1][si][0];
                        af.u[3] = pk[kk][1][si][1];
                        oacc[si][dn] = mfma16(af.v, vf, oacc[si][dn]);
                    }
                }
            }
        }
        // WAR: all LDS reads complete before next iter's staging overwrites
        asm volatile("s_waitcnt lgkmcnt(0)" ::: "memory");
        __builtin_amdgcn_s_barrier();
        __builtin_amdgcn_sched_barrier(0);
    }

    const int b = bh / NHEAD, h = bh % NHEAD;
#pragma unroll
    for (int si = 0; si < 2; si++) {
        int ri = i0w + si * 16 + q4 * 4;
#pragma unroll
        for (int dn = 0; dn < 4; dn++) {
            int d = dn * 16 + m16;
#pragma unroll
            for (int r = 0; r < 4; r++) {
                Out[((size_t)b * TSEQ + ri + r) * CDIM + h * HD + d] = oacc[si][dn][r];
            }
        }
    }
}

// ---------------- launch ----------------
extern "C" void kernel_launch(void* const* d_in, const int* in_sizes, int n_in,
                              void* d_out, int out_size, void* d_ws, size_t ws_size,
                              hipStream_t stream) {
    const float* X    = (const float*)d_in[0];
    const float* W    = (const float*)d_in[1];
    const float* Bias = (const float*)d_in[2];
    float* out = (float*)d_out;

    unsigned short* Xb = (unsigned short*)d_ws;
    unsigned short* Wt = Xb + (size_t)MROWS * CDIM;
    unsigned short* Q  = Wt + (size_t)NQKV * CDIM;
    unsigned short* Km = Q  + (size_t)BHTOT * TSEQ * HD;
    unsigned short* Vt = Km + (size_t)BHTOT * TSEQ * HD;

    hipLaunchKernelGGL(prep, dim3(448), dim3(256), 0, stream, X, W, Xb, Wt);
    hipLaunchKernelGGL(qkv_gemm, dim3(576), dim3(512), 0, stream,
                       Xb, Wt, Bias, Q, Km, Vt);
    hipLaunchKernelGGL(attn, dim3(BHTOT * 8), dim3(512), 0, stream, Q, Km, Vt, out);
}

// Round 8
// 213.583 us; speedup vs baseline: 1.0182x; 1.0182x over previous
//
#include <hip/hip_runtime.h>
#include <hip/hip_bf16.h>

// ---------------- types & helpers ----------------
typedef short bf16x8 __attribute__((ext_vector_type(8)));
typedef float f32x4  __attribute__((ext_vector_type(4)));
typedef unsigned short u16x4 __attribute__((ext_vector_type(4)));

#define CDIM   768
#define NQKV   2304
#define MROWS  8192
#define TSEQ   2048
#define HD     64
#define NHEAD  12
#define BHTOT  48

__device__ __forceinline__ unsigned short f2bf(float f) {
    unsigned int x;
    __builtin_memcpy(&x, &f, 4);
    unsigned int r = (x + 0x7fffu + ((x >> 16) & 1u)) >> 16;
    return (unsigned short)r;
}

__device__ __forceinline__ unsigned int pkbf(float a, float b) {
    unsigned int ua, ub;
    __builtin_memcpy(&ua, &a, 4);
    __builtin_memcpy(&ub, &b, 4);
    return __builtin_amdgcn_perm(ua + 0x8000u, ub + 0x8000u, 0x03020706u);
}

__device__ __forceinline__ f32x4 mfma16(bf16x8 a, bf16x8 b, f32x4 c) {
    return __builtin_amdgcn_mfma_f32_16x16x32_bf16(a, b, c, 0, 0, 0);
}

__device__ __forceinline__ void gl_lds16(const unsigned short* g, unsigned short* l) {
    __builtin_amdgcn_global_load_lds(
        (__attribute__((address_space(1))) void*)(g),
        (__attribute__((address_space(3))) void*)(l),
        16, 0, 0);
}

// ---------------- kernel 0: prep = W transpose+cvt + X cvt ----------------
__global__ __launch_bounds__(256) void prep(
    const float* __restrict__ X, const float* __restrict__ W,
    unsigned short* __restrict__ Xb, unsigned short* __restrict__ Wt)
{
    const int tid = threadIdx.x, blk = blockIdx.x;
    if (blk < 432) {
        __shared__ __align__(16) unsigned short tile[64][72];
        const int bx = blk % 36, by = blk / 36;
#pragma unroll
        for (int c = 0; c < 4; c++) {
            int chunk = tid + 256 * c;
            int r = chunk >> 4, cc = chunk & 15;
            f32x4 v = *(const f32x4*)(W + (size_t)(by * 64 + r) * NQKV + bx * 64 + cc * 4);
#pragma unroll
            for (int j = 0; j < 4; j++) tile[cc * 4 + j][r] = f2bf(v[j]);
        }
        __syncthreads();
#pragma unroll
        for (int c = 0; c < 2; c++) {
            int chunk = tid + 256 * c;
            int r = chunk >> 3, cc = chunk & 7;
            bf16x8 v;
#pragma unroll
            for (int j = 0; j < 8; j++) v[j] = (short)tile[r][cc * 8 + j];
            *(bf16x8*)(Wt + (size_t)(bx * 64 + r) * CDIM + by * 64 + cc * 8) = v;
        }
    }
    for (size_t i4 = (size_t)blk * 256 + tid; i4 < (size_t)(MROWS * CDIM / 4);
         i4 += (size_t)448 * 256) {
        f32x4 v = *(const f32x4*)(X + i4 * 4);
        u16x4 o;
#pragma unroll
        for (int j = 0; j < 4; j++) o[j] = f2bf(v[j]);
        *(u16x4*)(Xb + i4 * 4) = o;
    }
}

// ---------------- kernel 1: QKV GEMM (BM=256, BN=128, BK=64, 512 thr) ----------------
// R0 baseline (proven 57.5us profiled). 8 waves, each 64x64. XOR-swizzled LDS,
// conflict-free b128 reads. Q pre-scaled by 0.125. XCD-colocated m-tiles.
#define BK 64

__global__ __launch_bounds__(512, 4) void qkv_gemm(
    const unsigned short* __restrict__ X,    // (8192, 768) bf16
    const unsigned short* __restrict__ Wt,   // (2304, 768) bf16
    const float* __restrict__ Bias,          // (2304) fp32
    unsigned short* __restrict__ Q,
    unsigned short* __restrict__ Km,
    unsigned short* __restrict__ Vt)
{
    __shared__ __align__(16) unsigned short As[256 * BK];  // 32 KB
    __shared__ __align__(16) unsigned short Bs[128 * BK];  // 16 KB
    const int tid  = threadIdx.x;
    const int wave = tid >> 6, lane = tid & 63;
    const int quad = lane >> 4, m16 = lane & 15;
    const int wr = wave >> 1, wc = wave & 1;

    const int t   = blockIdx.x;                // 0..575
    const int xcd = t & 7, s = t >> 3;         // s: 0..71
    const int m0  = (xcd * 4 + (s & 3)) * 256;
    const int n0  = (s >> 2) * 128;

    f32x4 acc[4][4];
#pragma unroll
    for (int i = 0; i < 4; i++)
#pragma unroll
        for (int j = 0; j < 4; j++) acc[i][j] = f32x4{0.f, 0.f, 0.f, 0.f};

    const unsigned short* xb = X + (size_t)m0 * CDIM;
    const unsigned short* wb = Wt + (size_t)n0 * CDIM;

    const int spos = lane & 7;
    const int rb = m16 & 7;
    int arow[4], brow[2];
#pragma unroll
    for (int c = 0; c < 4; c++) arow[c] = (wave * 256 + c * 64 + lane) >> 3;
#pragma unroll
    for (int c = 0; c < 2; c++) brow[c] = (wave * 128 + c * 64 + lane) >> 3;

    for (int k0 = 0; k0 < CDIM; k0 += BK) {
#pragma unroll
        for (int c = 0; c < 4; c++) {
            int row = arow[c], ch = spos ^ (row & 7);
            gl_lds16(xb + (size_t)row * CDIM + k0 + ch * 8, As + wave * 2048 + c * 512);
        }
#pragma unroll
        for (int c = 0; c < 2; c++) {
            int row = brow[c], ch = spos ^ (row & 7);
            gl_lds16(wb + (size_t)row * CDIM + k0 + ch * 8, Bs + wave * 1024 + c * 512);
        }
        __syncthreads();
#pragma unroll
        for (int ks = 0; ks < 2; ks++) {
            bf16x8 af[4], bfg[4];
#pragma unroll
            for (int u = 0; u < 4; u++) {
                int rowa = wr * 64 + u * 16 + m16;
                int rowb = wc * 64 + u * 16 + m16;
                int pos = (ks * 4 + quad) ^ rb;
                af[u]  = *(const bf16x8*)(As + rowa * 64 + pos * 8);
                bfg[u] = *(const bf16x8*)(Bs + rowb * 64 + pos * 8);
            }
#pragma unroll
            for (int i = 0; i < 4; i++)
#pragma unroll
                for (int j = 0; j < 4; j++)
                    acc[i][j] = mfma16(af[i], bfg[j], acc[i][j]);
        }
        __syncthreads();
    }

    const int region = n0 / CDIM;
    const float qscale = (region == 0) ? 0.125f : 1.0f;
#pragma unroll
    for (int i = 0; i < 4; i++) {
        int row = m0 + wr * 64 + i * 16 + quad * 4;
#pragma unroll
        for (int j = 0; j < 4; j++) {
            int gcol = n0 + wc * 64 + j * 16 + m16;
            int cc = gcol - region * CDIM;
            int h = cc >> 6, d = cc & 63;
            float bv = Bias[gcol];
#pragma unroll
            for (int r = 0; r < 4; r++) {
                int gm = row + r;
                int b = gm >> 11, tq = gm & 2047;
                int bh = b * NHEAD + h;
                unsigned short o = f2bf((acc[i][j][r] + bv) * qscale);
                if (region == 0)      Q[((size_t)bh * TSEQ + tq) * HD + d] = o;
                else if (region == 1) Km[((size_t)bh * TSEQ + tq) * HD + d] = o;
                else                  Vt[((size_t)bh * HD + d) * TSEQ + tq] = o;
            }
        }
    }
}

// ---------------- kernel 2: causal relu-attention (S^T formulation) ----------------
// R8 = R5 shell (4 waves, QBLK=128, proven masks) with:
//  (1) K double-buffered in LDS, cross-tile prefetch, ONE barrier per tile,
//      counted vmcnt(16) (never drains the prefetch) [T3/T4];
//  (2) V -> registers, issued BEFORE QK^T, consumed in PV a phase later [T14]
//      (V frags are wave-independent; kills the V LDS pass = the whole 1.67M
//      bank-conflict source; R6's mistake was loading V AT the PV site);
//  (3) snake (bh,it) ordering so each CU's ~3 blocks get complementary loads.
// LDS 32KB (K dbuf only). VGPR ~150 -> launch_bounds(256,3); 768 blocks @3/CU
// = one full round.
__global__ __launch_bounds__(256, 3) void attn(
    const unsigned short* __restrict__ Q,
    const unsigned short* __restrict__ Kmat,
    const unsigned short* __restrict__ Vt,
    float* __restrict__ Out)
{
    __shared__ __align__(16) unsigned short S[16384];  // K buf0 16KB | K buf1 16KB

    const int tid  = threadIdx.x;
    const int wave = tid >> 6, lane = tid & 63;
    const int q4 = lane >> 4, m16 = lane & 15;
    const int q8 = m16 >> 2, m3 = m16 & 3;

    const int xcd = blockIdx.x & 7;
    const int idx = blockIdx.x >> 3;        // 0..95 within XCD
    // snake order: CU slot p gets one block from each third with complementary it
    const int p = idx & 31, g = idx >> 5;
    const int r = (g == 0) ? p : ((g == 1) ? 95 - p : 32 + p);
    const int bh  = xcd * 6 + (r % 6);
    const int it  = 15 - (r / 6);
    const int i0  = it * 128;

    const unsigned short* qb = Q    + (size_t)bh * TSEQ * HD;
    const unsigned short* kb = Kmat + (size_t)bh * TSEQ * HD;
    const unsigned short* vb = Vt   + (size_t)bh * HD * TSEQ;

    bf16x8 qf[2][2];
#pragma unroll
    for (int si = 0; si < 2; si++)
#pragma unroll
        for (int ks = 0; ks < 2; ks++)
            qf[si][ks] = *(const bf16x8*)(qb +
                (size_t)(i0 + wave * 32 + si * 16 + m16) * HD + ks * 32 + q4 * 8);

    f32x4 oacc[2][4];
#pragma unroll
    for (int si = 0; si < 2; si++)
#pragma unroll
        for (int dn = 0; dn < 4; dn++) oacc[si][dn] = f32x4{0.f, 0.f, 0.f, 0.f};

    const int fr  = ((q8 & 1) << 2) | m3;
    const int kx0 = (q4 ^ fr) * 8;
    const int kx1 = kx0 ^ 32;
    const int krb = (q8 * 8 + m3) * 64;

    // per-wave K staging offsets (4 chunks of 1KB; swizzled source, linear dest)
    int ksrow[4], kschk[4];
#pragma unroll
    for (int cc = 0; cc < 4; cc++) {
        int cs = wave * 4 + cc;
        ksrow[cc] = cs * 8 + (lane >> 3);
        kschk[cc] = (lane & 7) ^ ((((ksrow[cc] >> 3) & 1) << 2) | (ksrow[cc] & 3));
    }

    // ---- prologue: issue K tile 0 into buf 0 (no wait; loop-top handles) ----
#pragma unroll
    for (int cc = 0; cc < 4; cc++)
        gl_lds16(kb + (size_t)ksrow[cc] * HD + kschk[cc] * 8,
                 S + (wave * 4 + cc) * 512);

    for (int jt = 0; jt <= it; jt++) {
        const int j0 = jt * 128;
        const unsigned short* Kb = S + (jt & 1) * 8192;

        // ---- A: issue all 16 V fragment loads (global -> VGPR), newest 16 ----
        bf16x8 vreg[16];
#pragma unroll
        for (int kk = 0; kk < 4; kk++)
#pragma unroll
            for (int dn = 0; dn < 4; dn++)
                vreg[kk * 4 + dn] = *(const bf16x8*)(vb +
                    (size_t)(dn * 16 + m16) * TSEQ + j0 + kk * 32 + q4 * 8);

        // ---- B: wait own K chunks (oldest 4; leave 16 V in flight), sync ----
        asm volatile("s_waitcnt vmcnt(16)" ::: "memory");
        __builtin_amdgcn_s_barrier();
        __builtin_amdgcn_sched_barrier(0);

        const bool diag = (jt == it);

        // ---- C: QK^T + mask + relu + pack, all kk ----
        unsigned int pk[4][2][2][2];
#pragma unroll
        for (int kk = 0; kk < 4; kk++) {
            const int kb0 = kk * 2048 + krb;
            bf16x8 kf_e0 = *(const bf16x8*)(Kb + kb0 + kx0);
            bf16x8 kf_e1 = *(const bf16x8*)(Kb + kb0 + kx1);
            bf16x8 kf_o0 = *(const bf16x8*)(Kb + kb0 + 256 + kx0);
            bf16x8 kf_o1 = *(const bf16x8*)(Kb + kb0 + 256 + kx1);

            f32x4 sacc[2][2];
#pragma unroll
            for (int o = 0; o < 2; o++)
#pragma unroll
                for (int si = 0; si < 2; si++) sacc[o][si] = f32x4{0.f, 0.f, 0.f, 0.f};
#pragma unroll
            for (int si = 0; si < 2; si++) {
                sacc[0][si] = mfma16(kf_e0, qf[si][0], sacc[0][si]);
                sacc[0][si] = mfma16(kf_e1, qf[si][1], sacc[0][si]);
                sacc[1][si] = mfma16(kf_o0, qf[si][0], sacc[1][si]);
                sacc[1][si] = mfma16(kf_o1, qf[si][1], sacc[1][si]);
            }

#pragma unroll
            for (int o = 0; o < 2; o++)
#pragma unroll
                for (int si = 0; si < 2; si++) {
                    f32x4 v = sacc[o][si];
                    if (diag) {
#pragma unroll
                        for (int rr = 0; rr < 4; rr++) {
                            int gj = kk * 32 + q4 * 8 + o * 4 + rr;
                            int gi = wave * 32 + si * 16 + m16;
                            if (gj > gi) v[rr] = 0.f;
                        }
                    }
#pragma unroll
                    for (int rr = 0; rr < 4; rr++) v[rr] = fmaxf(v[rr], 0.f);
                    pk[kk][o][si][0] = pkbf(v[0], v[1]);
                    pk[kk][o][si][1] = pkbf(v[2], v[3]);
                }
        }

        // ---- E: prefetch K tile jt+1 into the other buffer (unconditional,
        //         clamped so the last iter restages the same tile harmlessly) ----
        {
            const int jn = (jt < it) ? (j0 + 128) : j0;
#pragma unroll
            for (int cc = 0; cc < 4; cc++)
                gl_lds16(kb + (size_t)(jn + ksrow[cc]) * HD + kschk[cc] * 8,
                         S + ((jt & 1) ^ 1) * 8192 + (wave * 4 + cc) * 512);
        }

        // ---- G: PV from V registers (compiler emits counted vmcnt(4)) ----
#pragma unroll
        for (int kk = 0; kk < 4; kk++) {
#pragma unroll
            for (int dn = 0; dn < 4; dn++) {
#pragma unroll
                for (int si = 0; si < 2; si++) {
                    union { bf16x8 v; unsigned int u[4]; } af;
                    af.u[0] = pk[kk][0][si][0];
                    af.u[1] = pk[kk][0][si][1];
                    af.u[2] = pk[kk][1][si][0];
                    af.u[3] = pk[kk][1][si][1];
                    oacc[si][dn] = mfma16(af.v, vreg[kk * 4 + dn], oacc[si][dn]);
                }
            }
        }
    }

    const int b = bh / NHEAD, h = bh % NHEAD;
#pragma unroll
    for (int si = 0; si < 2; si++) {
        int ri = i0 + wave * 32 + si * 16 + q4 * 4;
#pragma unroll
        for (int dn = 0; dn < 4; dn++) {
            int d = dn * 16 + m16;
#pragma unroll
            for (int rr = 0; rr < 4; rr++) {
                Out[((size_t)b * TSEQ + ri + rr) * CDIM + h * HD + d] = oacc[si][dn][rr];
            }
        }
    }
}

// ---------------- launch ----------------
extern "C" void kernel_launch(void* const* d_in, const int* in_sizes, int n_in,
                              void* d_out, int out_size, void* d_ws, size_t ws_size,
                              hipStream_t stream) {
    const float* X    = (const float*)d_in[0];
    const float* W    = (const float*)d_in[1];
    const float* Bias = (const float*)d_in[2];
    float* out = (float*)d_out;

    unsigned short* Xb = (unsigned short*)d_ws;
    unsigned short* Wt = Xb + (size_t)MROWS * CDIM;
    unsigned short* Q  = Wt + (size_t)NQKV * CDIM;
    unsigned short* Km = Q  + (size_t)BHTOT * TSEQ * HD;
    unsigned short* Vt = Km + (size_t)BHTOT * TSEQ * HD;

    hipLaunchKernelGGL(prep, dim3(448), dim3(256), 0, stream, X, W, Xb, Wt);
    hipLaunchKernelGGL(qkv_gemm, dim3(576), dim3(512), 0, stream,
                       Xb, Wt, Bias, Q, Km, Vt);
    hipLaunchKernelGGL(attn, dim3(BHTOT * 16), dim3(256), 0, stream, Q, Km, Vt, out);
}